// Round 1
// baseline (618.443 us; speedup 1.0000x reference)
//
#include <hip/hip_runtime.h>
#include <math.h>

// Problem constants
#define K_CODES 1024
#define DIM 256
#define BB 32
#define TT 2048
#define NROWS (BB * TT)            // 65536
#define QN (BB * DIM * TT)         // 16777216
#define LOSS_OFF QN
#define IDX_OFF (QN + 1)

// ws layout (in floats)
#define WS_E2 0
#define WS_SX 1024
#define WS_LOSS (1024 + NROWS)

// numpy pairwise_sum replica for 256 elements of squares:
// S256 = S128(a[0:128]) + S128(a[128:256]); S128 = 8-accumulator unrolled,
// combined as ((r0+r1)+(r2+r3)) + ((r4+r5)+(r6+r7)). All ops forced rn.
__device__ __forceinline__ float pw128_sq(const float* p, int stride) {
    float r[8];
#pragma unroll
    for (int j = 0; j < 8; ++j) {
        float v = p[j * stride];
        r[j] = __fmul_rn(v, v);
    }
#pragma unroll
    for (int i = 8; i < 128; i += 8) {
#pragma unroll
        for (int j = 0; j < 8; ++j) {
            float v = p[(i + j) * stride];
            r[j] = __fadd_rn(r[j], __fmul_rn(v, v));
        }
    }
    return __fadd_rn(__fadd_rn(__fadd_rn(r[0], r[1]), __fadd_rn(r[2], r[3])),
                     __fadd_rn(__fadd_rn(r[4], r[5]), __fadd_rn(r[6], r[7])));
}

__device__ __forceinline__ float pw256_sq(const float* p, int stride) {
    return __fadd_rn(pw128_sq(p, stride), pw128_sq(p + 128 * stride, stride));
}

// Kernel 1a: codebook squared norms (numpy-pairwise) + zero the loss accumulator.
__global__ void k_prep_e2(const float* __restrict__ emb, float* __restrict__ ws) {
    int k = blockIdx.x * 256 + threadIdx.x;
    if (k == 0) ws[WS_LOSS] = 0.0f;
    if (k < K_CODES) ws[WS_E2 + k] = pw256_sq(emb + (size_t)k * DIM, 1);
}

// Kernel 1b: per-row squared norms of x (numpy-pairwise). Row n=(b,t): x[d]=in[b][d][t].
// Lanes = consecutive t -> every d-step is a coalesced 256B run.
__global__ void k_prep_sx(const float* __restrict__ in, float* __restrict__ ws) {
    int row = blockIdx.x * 256 + threadIdx.x;
    int b = row >> 11;
    int t = row & (TT - 1);
    ws[WS_SX + row] = pw256_sq(in + (size_t)b * (DIM * TT) + t, TT);
}

// Kernel 2: distance GEMM + argmin + gather + transpose write + loss partial sums.
// Block: 256 threads = 16(tx code-groups) x 16(ty row-groups), 8x8 regs each.
// Tile: 128 rows x 128 codes per chunk, 8 code chunks, 8 d-chunks of 32.
__launch_bounds__(256, 2)
__global__ void k_main(const float* __restrict__ in, const float* __restrict__ emb,
                       const float* __restrict__ ws, float* __restrict__ wloss,
                       float* __restrict__ out) {
    __shared__ float smem[8192];       // xs[128*32] | es[128*32]; reused for reduce & q staging
    __shared__ int idx_lds[128];
    float* xs = smem;
    float* es = smem + 4096;

    const int tid = threadIdx.x;
    const int tx = tid & 15;
    const int ty = tid >> 4;
    const int row0 = blockIdx.x * 128;
    const int b = row0 >> 11;          // row0 / 2048
    const int t0 = row0 & (TT - 1);
    const float* xbase = in + (size_t)b * (DIM * TT) + t0;   // + d*TT + r

    // preload row norms for my 8 rows
    float sxr[8];
#pragma unroll
    for (int i = 0; i < 8; ++i) sxr[i] = ws[WS_SX + row0 + 8 * ty + i];

    float bestd[8];
    int bestidx[8];
#pragma unroll
    for (int i = 0; i < 8; ++i) { bestd[i] = INFINITY; bestidx[i] = 0; }

    const int lr = tid & 127;   // x-load row
    const int lh = tid >> 7;    // x-load half (c4 parity)

    for (int cc = 0; cc < 8; ++cc) {
        const int cbase = cc * 128;
        float acc[8][8];
#pragma unroll
        for (int i = 0; i < 8; ++i)
#pragma unroll
            for (int j = 0; j < 8; ++j) acc[i][j] = 0.0f;

        for (int dc = 0; dc < 8; ++dc) {
            const int d0 = dc * 32;
            __syncthreads();
            // Stage x chunk: logical xs[r][c] = in[b][d0+c][t0+r], c=0..31.
            // XOR-swizzled float4 chunks: chunk c4 of row r stored at c4 ^ ((r>>3)&7).
#pragma unroll
            for (int it = 0; it < 4; ++it) {
                int c4 = lh + 2 * it;
                float v0 = xbase[(size_t)(d0 + 4 * c4 + 0) * TT + lr];
                float v1 = xbase[(size_t)(d0 + 4 * c4 + 1) * TT + lr];
                float v2 = xbase[(size_t)(d0 + 4 * c4 + 2) * TT + lr];
                float v3 = xbase[(size_t)(d0 + 4 * c4 + 3) * TT + lr];
                int cs = c4 ^ ((lr >> 3) & 7);
                *(float4*)&xs[lr * 32 + cs * 4] = make_float4(v0, v1, v2, v3);
            }
            // Stage e chunk: es[code][c] = emb[cbase+code][d0+c], same swizzle.
#pragma unroll
            for (int it = 0; it < 4; ++it) {
                int s = tid + 256 * it;
                int code = s >> 3;
                int c4 = s & 7;
                float4 v = *(const float4*)&emb[(size_t)(cbase + code) * DIM + d0 + c4 * 4];
                int cs = c4 ^ ((code >> 3) & 7);
                *(float4*)&es[code * 32 + cs * 4] = v;
            }
            __syncthreads();
            // Accumulate: strict ascending-d fma chain per (row, code) accumulator.
#pragma unroll
            for (int c4 = 0; c4 < 8; ++c4) {
                float4 xv[8], ev[8];
                const int xc = (c4 ^ (ty & 7)) * 4;
                const int ec = (c4 ^ (tx & 7)) * 4;
#pragma unroll
                for (int i = 0; i < 8; ++i) xv[i] = *(const float4*)&xs[(8 * ty + i) * 32 + xc];
#pragma unroll
                for (int j = 0; j < 8; ++j) ev[j] = *(const float4*)&es[(8 * tx + j) * 32 + ec];
#pragma unroll
                for (int i = 0; i < 8; ++i)
#pragma unroll
                    for (int j = 0; j < 8; ++j) {
                        float a = acc[i][j];
                        a = __fmaf_rn(xv[i].x, ev[j].x, a);
                        a = __fmaf_rn(xv[i].y, ev[j].y, a);
                        a = __fmaf_rn(xv[i].z, ev[j].z, a);
                        a = __fmaf_rn(xv[i].w, ev[j].w, a);
                        acc[i][j] = a;
                    }
            }
        }
        // Distances for this code chunk. Replicate np expression:
        // dist = fl( fl(sx + e2) - fl(2*dot) ); scan ascending code (j asc per cc asc)
        // with strict < keeps lowest index on exact ties.
#pragma unroll
        for (int j = 0; j < 8; ++j) {
            const int code = cbase + 8 * tx + j;
            const float e2 = ws[WS_E2 + code];
#pragma unroll
            for (int i = 0; i < 8; ++i) {
                float dist = __fsub_rn(__fadd_rn(sxr[i], e2), __fmul_rn(2.0f, acc[i][j]));
                if (dist < bestd[i]) { bestd[i] = dist; bestidx[i] = code; }
            }
        }
    }

    // Cross-thread argmin reduction (16 candidates per row), lexicographic (dist, idx).
    __syncthreads();
    float* rd = smem;                   // [128][16]
    int* ri = (int*)(smem + 2048);      // [128][16]
#pragma unroll
    for (int i = 0; i < 8; ++i) {
        rd[(8 * ty + i) * 16 + tx] = bestd[i];
        ri[(8 * ty + i) * 16 + tx] = bestidx[i];
    }
    __syncthreads();
    if (tid < 128) {
        float bd = rd[tid * 16];
        int bi = ri[tid * 16];
#pragma unroll
        for (int x = 1; x < 16; ++x) {
            float d = rd[tid * 16 + x];
            int ix = ri[tid * 16 + x];
            if (d < bd || (d == bd && ix < bi)) { bd = d; bi = ix; }
        }
        idx_lds[tid] = bi;
        out[IDX_OFF + b * TT + t0 + tid] = (float)bi;  // indices output as fp32 values
    }
    __syncthreads();

    // Epilogue: quantized = gather(emb, idx) written back as [B][D][T]; loss partials.
    float lsum = 0.0f;
    float* q = smem;                    // [128][37] (pad 37 breaks bank conflicts)
    const int qr = tid >> 3;            // 0..31 (+32*it)
    const int qf = tid & 7;
    const int er_ = tid & 127;
    const int ed_ = tid >> 7;
    for (int dc = 0; dc < 8; ++dc) {
        const int d0 = dc * 32;
        __syncthreads();
#pragma unroll
        for (int it = 0; it < 4; ++it) {
            int r = qr + 32 * it;
            float4 v = *(const float4*)&emb[(size_t)idx_lds[r] * DIM + d0 + qf * 4];
            float* dst = &q[r * 37 + qf * 4];
            dst[0] = v.x; dst[1] = v.y; dst[2] = v.z; dst[3] = v.w;
        }
        __syncthreads();
#pragma unroll
        for (int k = 0; k < 16; ++k) {
            int dd = ed_ + 2 * k;
            float qq = q[er_ * 37 + dd];
            size_t gaddr = (size_t)b * (DIM * TT) + (size_t)(d0 + dd) * TT + t0 + er_;
            float xx = in[gaddr];
            out[gaddr] = qq;
            float df = __fsub_rn(qq, xx);
            lsum = __fmaf_rn(df, df, lsum);
        }
    }
    // wave reduce + one atomic per wave
#pragma unroll
    for (int off = 32; off > 0; off >>= 1) lsum += __shfl_down(lsum, off, 64);
    if ((tid & 63) == 0) atomicAdd(wloss, lsum);
}

// Kernel 3: finalize loss = (1 + 0.25) * mean((q - x)^2)
__global__ void k_loss(const float* __restrict__ wloss, float* __restrict__ out) {
    out[LOSS_OFF] = 1.25f * wloss[0] / 16777216.0f;
}

extern "C" void kernel_launch(void* const* d_in, const int* in_sizes, int n_in,
                              void* d_out, int out_size, void* d_ws, size_t ws_size,
                              hipStream_t stream) {
    const float* in = (const float*)d_in[0];
    const float* emb = (const float*)d_in[1];
    float* out = (float*)d_out;
    float* ws = (float*)d_ws;

    hipLaunchKernelGGL(k_prep_e2, dim3(4), dim3(256), 0, stream, emb, ws);
    hipLaunchKernelGGL(k_prep_sx, dim3(256), dim3(256), 0, stream, in, ws);
    hipLaunchKernelGGL(k_main, dim3(512), dim3(256), 0, stream, in, emb, ws,
                       ws + WS_LOSS, out);
    hipLaunchKernelGGL(k_loss, dim3(1), dim3(1), 0, stream, ws + WS_LOSS, out);
}